// Round 9
// baseline (855.727 us; speedup 1.0000x reference)
//
#include <hip/hip_runtime.h>
#include <math.h>

#define NDIM 1024
#define HDIM 128
#define NB 256
#define NT 72
#define NR 36
#define KS 4  // split-K for simtile

// Whole-kernel attribution reps (idempotent bodies; runtime arg defeats folding)
#define R_FRONT 4
#define R_MID 16
#define R_L2 24
#define R_ST 16
#define R_RED 64

__device__ __forceinline__ float wave_sum(float v) {
#pragma unroll
  for (int off = 32; off > 0; off >>= 1) v += __shfl_down(v, off, 64);
  return v;
}

__device__ __forceinline__ float dot4(const float4 a, const float4 b) {
  return a.x * b.x + a.y * b.y + a.z * b.z + a.w * b.w;
}

// K1: blocks 0..511 cap partial sums; 512..767 image mean + l2norm.
__global__ __launch_bounds__(256) void k_front(const float* img, const float* cap,
                                               const int* lens, float* fs, float* fq, float* ms,
                                               float* repr, float* imgn, int reps) {
  const int bid = blockIdx.x, tid = threadIdx.x;
  __shared__ float red[4];
  __shared__ float sInv;
  if (bid < 512) {
    const int b = bid & 255;
    const int half = bid >> 8;
    const int len = lens[b];
    const int t0 = half * 36;
    const float* base = cap + (size_t)b * NT * NDIM + (size_t)t0 * NDIM + tid * 4;
    const int o = (half * NB + b) * NDIM + tid * 4;
#pragma unroll 1
    for (int r = 0; r < reps; ++r) {
      float fsx = 0.f, fsy = 0.f, fsz = 0.f, fsw = 0.f;
      float fqx = 0.f, fqy = 0.f, fqz = 0.f, fqw = 0.f;
      float msx = 0.f, msy = 0.f, msz = 0.f, msw = 0.f;
#pragma unroll 12
      for (int tt = 0; tt < 36; ++tt) {
        const float4 v = *reinterpret_cast<const float4*>(base + tt * NDIM);
        fsx += v.x; fsy += v.y; fsz += v.z; fsw += v.w;
        fqx += v.x * v.x; fqy += v.y * v.y; fqz += v.z * v.z; fqw += v.w * v.w;
        if (t0 + tt < len) { msx += v.x; msy += v.y; msz += v.z; msw += v.w; }
      }
      *reinterpret_cast<float4*>(fs + o) = make_float4(fsx, fsy, fsz, fsw);
      *reinterpret_cast<float4*>(fq + o) = make_float4(fqx, fqy, fqz, fqw);
      *reinterpret_cast<float4*>(ms + o) = make_float4(msx, msy, msz, msw);
    }
  } else {
    const int b = bid - 512;
    const float* base = img + (size_t)b * NR * NDIM + tid * 4;
    const int lane = tid & 63, wv = tid >> 6;
#pragma unroll 1
    for (int r = 0; r < reps; ++r) {
      float sx = 0.f, sy = 0.f, sz = 0.f, sw = 0.f;
#pragma unroll 12
      for (int rr = 0; rr < NR; ++rr) {
        const float4 v = *reinterpret_cast<const float4*>(base + rr * NDIM);
        sx += v.x; sy += v.y; sz += v.z; sw += v.w;
      }
      const float inv = 1.0f / (float)NR;
      sx *= inv; sy *= inv; sz *= inv; sw *= inv;
      *reinterpret_cast<float4*>(repr + (size_t)b * NDIM + tid * 4) = make_float4(sx, sy, sz, sw);
      const float sq = wave_sum(sx * sx + sy * sy + sz * sz + sw * sw);
      if (lane == 0) red[wv] = sq;
      __syncthreads();
      if (tid == 0) sInv = 1.0f / (sqrtf(red[0] + red[1] + red[2] + red[3]) + 1e-8f);
      __syncthreads();
      const float iv = sInv;
      *reinterpret_cast<float4*>(imgn + (size_t)b * NDIM + tid * 4) =
          make_float4(sx * iv, sy * iv, sz * iv, sw * iv);
    }
  }
}

// K2: blocks 0..15 BN stats + pooled; blocks 16..527 layer1 split-K GEMM.
__global__ __launch_bounds__(512) void k_mid(const float* fs, const float* fq, const float* ms,
                                             const int* lens, const float* repr,
                                             const float* Wg1, const float* Wb1, float* pooled,
                                             float* hpart, int reps) {
  const int bid = blockIdx.x, tid = threadIdx.x;
  __shared__ float ss[8][64], sq2[8][64], smu[64], srs[64];
  __shared__ float shr[8][128];
  __shared__ float sacc[8][128][8];
  if (bid < 16) {
    const int d0 = bid * 64, dloc = tid & 63, grp = tid >> 6;
    const int r0 = grp * 64;
#pragma unroll 1
    for (int r = 0; r < reps; ++r) {
      float s = 0.f, q = 0.f;
#pragma unroll 8
      for (int rr = r0; rr < r0 + 64; ++rr) {
        s += fs[(size_t)rr * NDIM + d0 + dloc];
        q += fq[(size_t)rr * NDIM + d0 + dloc];
      }
      ss[grp][dloc] = s;
      sq2[grp][dloc] = q;
      __syncthreads();
      if (tid < 64) {
        float S = 0.f, Q = 0.f;
#pragma unroll
        for (int g2 = 0; g2 < 8; ++g2) { S += ss[g2][tid]; Q += sq2[g2][tid]; }
        const float invN = 1.0f / (float)(NB * NT);
        const float mu = S * invN;
        const float var = Q * invN - mu * mu;
        smu[tid] = mu;
        srs[tid] = 1.0f / sqrtf(var + 1e-5f);
      }
      __syncthreads();
      const int dcol = tid & 63, brow = tid >> 6;
      const float mu = smu[dcol], rs = srs[dcol];
#pragma unroll 4
      for (int b = brow; b < NB; b += 8) {
        const float invl = 1.0f / (float)lens[b];
        const float m =
            ms[(size_t)b * NDIM + d0 + dcol] + ms[(size_t)(NB + b) * NDIM + d0 + dcol];
        pooled[(size_t)b * NDIM + d0 + dcol] = (m * invl - mu) * rs;
      }
      __syncthreads();
    }
  } else {
    const int idx = bid - 16;
    const int g = idx & 31, br = (idx >> 5) & 1, ks = idx >> 6;
    const int b0 = g * 8;
    const int kbase = ks * 128;
    const int h2 = tid & 63;
    const int ksub = tid >> 6;
    const float* W = br ? Wb1 : Wg1;
#pragma unroll 1
    for (int r = 0; r < reps; ++r) {
      {
        const int im = tid >> 6, c2 = (tid & 63) * 2;
        *reinterpret_cast<float2*>(&shr[im][c2]) =
            *reinterpret_cast<const float2*>(repr + (size_t)(b0 + im) * NDIM + kbase + c2);
      }
      __syncthreads();
      float acc0[8] = {0, 0, 0, 0, 0, 0, 0, 0}, acc1[8] = {0, 0, 0, 0, 0, 0, 0, 0};
#pragma unroll
      for (int q = 0; q < 4; ++q) {
        const int dl = ksub * 16 + q * 4;
        const float* wq = W + (size_t)(kbase + dl) * HDIM + h2;
        const float wa0 = wq[0], wa1 = wq[128], wa2 = wq[256], wa3 = wq[384];
        const float wb0 = wq[64], wb1 = wq[192], wb2 = wq[320], wb3 = wq[448];
#pragma unroll
        for (int i = 0; i < 8; ++i) {
          const float4 s = *reinterpret_cast<const float4*>(&shr[i][dl]);
          acc0[i] += s.x * wa0 + s.y * wa1 + s.z * wa2 + s.w * wa3;
          acc1[i] += s.x * wb0 + s.y * wb1 + s.z * wb2 + s.w * wb3;
        }
      }
      __syncthreads();
#pragma unroll
      for (int i = 0; i < 8; ++i) {
        sacc[ksub][h2][i] = acc0[i];
        sacc[ksub][h2 + 64][i] = acc1[i];
      }
      __syncthreads();
#pragma unroll
      for (int v = tid; v < 1024; v += 512) {
        const int hh = v & 127, im = v >> 7;
        float s = 0.f;
#pragma unroll
        for (int k2 = 0; k2 < 8; ++k2) s += sacc[k2][hh][im];
        hpart[(((size_t)ks * 2 + br) * NB + b0 + im) * HDIM + hh] = s;
      }
    }
  }
}

// K3: hidden-reduce + layer2 + derived u,a,2bv,c,e. imgn is now a DEDICATED
// buffer (no aarr alias) so the body is idempotent under reps.
__global__ __launch_bounds__(512) void k_l2(const float* hpart, const float* bg1,
                                            const float* bb1, const float* Wg2, const float* bg2,
                                            const float* Wb2, const float* bb2, const float* imgn,
                                            float* uarr, float* aarr, float* bvarr, float* cpart,
                                            float* epart, int reps) {
  const int gb = blockIdx.x, dgrp = blockIdx.y;
  const int b0 = gb * 8;
  const int tid = threadIdx.x;
  __shared__ float shh[2][8][HDIM];
  __shared__ float sga[8][HDIM];
  __shared__ float sba[8][HDIM];
#pragma unroll 1
  for (int r = 0; r < reps; ++r) {
    {
      const int hh4 = (tid & 31) * 4;
      const int imA = (tid >> 5) & 7;
      const int brA = tid >> 8;
      float4 acc = make_float4(0.f, 0.f, 0.f, 0.f);
      const float* hp = hpart + ((size_t)brA * NB + b0 + imA) * HDIM + hh4;
#pragma unroll
      for (int ks = 0; ks < 8; ++ks) {
        const float4 v = *reinterpret_cast<const float4*>(hp + (size_t)ks * 2 * NB * HDIM);
        acc.x += v.x; acc.y += v.y; acc.z += v.z; acc.w += v.w;
      }
      const float4 bias = *reinterpret_cast<const float4*>((brA ? bb1 : bg1) + hh4);
      *reinterpret_cast<float4*>(&shh[brA][imA][hh4]) =
          make_float4(fmaxf(acc.x + bias.x, 0.f), fmaxf(acc.y + bias.y, 0.f),
                      fmaxf(acc.z + bias.z, 0.f), fmaxf(acc.w + bias.w, 0.f));
    }
    __syncthreads();
    const int dq = tid & 31;
    const int im = (tid >> 5) & 7;
    const int hs = tid >> 8;
    const int d = dgrp * 128 + dq * 4;
    float4 ga = make_float4(0.f, 0.f, 0.f, 0.f), ba = make_float4(0.f, 0.f, 0.f, 0.f);
    const int h0 = hs * 64;
#pragma unroll 8
    for (int h = h0; h < h0 + 64; ++h) {
      const float4 wg = *reinterpret_cast<const float4*>(Wg2 + (size_t)h * NDIM + d);
      const float4 wb = *reinterpret_cast<const float4*>(Wb2 + (size_t)h * NDIM + d);
      const float hg = shh[0][im][h], hb = shh[1][im][h];
      ga.x += hg * wg.x; ga.y += hg * wg.y; ga.z += hg * wg.z; ga.w += hg * wg.w;
      ba.x += hb * wb.x; ba.y += hb * wb.y; ba.z += hb * wb.z; ba.w += hb * wb.w;
    }
    if (hs) {
      *reinterpret_cast<float4*>(&sga[im][dq * 4]) = ga;
      *reinterpret_cast<float4*>(&sba[im][dq * 4]) = ba;
    }
    __syncthreads();
    if (!hs) {
      const float4 g2 = *reinterpret_cast<const float4*>(&sga[im][dq * 4]);
      const float4 b2 = *reinterpret_cast<const float4*>(&sba[im][dq * 4]);
      const float4 bgv = *reinterpret_cast<const float4*>(bg2 + d);
      const float4 bbv = *reinterpret_cast<const float4*>(bb2 + d);
      const float ox = ga.x + g2.x + bgv.x + 1.0f, oy = ga.y + g2.y + bgv.y + 1.0f;
      const float oz = ga.z + g2.z + bgv.z + 1.0f, ow = ga.w + g2.w + bgv.w + 1.0f;
      const float tx = ba.x + b2.x + bbv.x, ty = ba.y + b2.y + bbv.y;
      const float tz = ba.z + b2.z + bbv.z, tw = ba.w + b2.w + bbv.w;
      const size_t o = (size_t)(b0 + im) * NDIM + d;
      const float4 nv = *reinterpret_cast<const float4*>(imgn + o);
      *reinterpret_cast<float4*>(uarr + o) =
          make_float4(nv.x * ox, nv.y * oy, nv.z * oz, nv.w * ow);
      *reinterpret_cast<float4*>(aarr + o) = make_float4(ox * ox, oy * oy, oz * oz, ow * ow);
      *reinterpret_cast<float4*>(bvarr + o) =
          make_float4(2.0f * ox * tx, 2.0f * oy * ty, 2.0f * oz * tz, 2.0f * ow * tw);
      float c = nv.x * tx + nv.y * ty + nv.z * tz + nv.w * tw;
      float e = tx * tx + ty * ty + tz * tz + tw * tw;
#pragma unroll
      for (int off = 16; off > 0; off >>= 1) {
        c += __shfl_down(c, off, 32);
        e += __shfl_down(e, off, 32);
      }
      if ((tid & 31) == 0) {
        cpart[dgrp * NB + b0 + im] = c;
        epart[dgrp * NB + b0 + im] = e;
      }
    }
    __syncthreads();
  }
}

// K4: 3-dot tile kernel; 32x32 tile, 2x2 per thread, q=p^2 in regs,
// denominator pre-combined. grid (8,8,KS=4), 256 thr, K-chunk 256.
__global__ __launch_bounds__(256) void k_simtile(const float* uarr, const float* aarr,
                                                 const float* bvarr, const float* pooled,
                                                 float* pn, float* pd, int reps) {
  __shared__ float su[32][36], sa[32][36], sb[32][36], sp[32][36];
  const int tid = threadIdx.x;
  const int tx = tid & 15, ty = tid >> 4;
  const int i0 = blockIdx.x * 32, j0 = blockIdx.y * 32;
  const int k0 = blockIdx.z * (NDIM / KS);
  const int lr = tid >> 3;       // 0..31
  const int lc = (tid & 7) * 4;  // 0..28
  const int s = blockIdx.z;
#pragma unroll 1
  for (int r = 0; r < reps; ++r) {
    float an[2][2] = {{0.f, 0.f}, {0.f, 0.f}}, ad[2][2] = {{0.f, 0.f}, {0.f, 0.f}};
    for (int dc = k0; dc < k0 + NDIM / KS; dc += 32) {
      __syncthreads();
      *reinterpret_cast<float4*>(&su[lr][lc]) =
          *reinterpret_cast<const float4*>(uarr + (size_t)(i0 + lr) * NDIM + dc + lc);
      *reinterpret_cast<float4*>(&sa[lr][lc]) =
          *reinterpret_cast<const float4*>(aarr + (size_t)(i0 + lr) * NDIM + dc + lc);
      *reinterpret_cast<float4*>(&sb[lr][lc]) =
          *reinterpret_cast<const float4*>(bvarr + (size_t)(i0 + lr) * NDIM + dc + lc);
      *reinterpret_cast<float4*>(&sp[lr][lc]) =
          *reinterpret_cast<const float4*>(pooled + (size_t)(j0 + lr) * NDIM + dc + lc);
      __syncthreads();
#pragma unroll
      for (int dd = 0; dd < 32; dd += 4) {
        float4 rp[2], rq[2];
#pragma unroll
        for (int n = 0; n < 2; ++n) {
          rp[n] = *reinterpret_cast<const float4*>(&sp[ty + 16 * n][dd]);
          rq[n] = make_float4(rp[n].x * rp[n].x, rp[n].y * rp[n].y, rp[n].z * rp[n].z,
                              rp[n].w * rp[n].w);
        }
#pragma unroll
        for (int m = 0; m < 2; ++m) {
          const float4 ru = *reinterpret_cast<const float4*>(&su[tx + 16 * m][dd]);
          const float4 ra = *reinterpret_cast<const float4*>(&sa[tx + 16 * m][dd]);
          const float4 rb = *reinterpret_cast<const float4*>(&sb[tx + 16 * m][dd]);
#pragma unroll
          for (int n = 0; n < 2; ++n) {
            an[m][n] += dot4(ru, rp[n]);
            ad[m][n] += dot4(ra, rq[n]) + dot4(rb, rp[n]);
          }
        }
      }
    }
#pragma unroll
    for (int m = 0; m < 2; ++m) {
#pragma unroll
      for (int n = 0; n < 2; ++n) {
        const int i = i0 + tx + 16 * m, j = j0 + ty + 16 * n;
        const size_t o = ((size_t)s * NB + j) * NB + i;
        pn[o] = an[m][n];
        pd[o] = ad[m][n];
      }
    }
    __syncthreads();
  }
}

// K5: split-K combine + epilogue (KS=4 now)
__global__ __launch_bounds__(256) void k_reduce(const float* pn, const float* pd,
                                                const float* cpart, const float* epart,
                                                float* out, int reps) {
  const int j = blockIdx.x, i = threadIdx.x;
  const size_t base = (size_t)j * NB + i;
#pragma unroll 1
  for (int r = 0; r < reps; ++r) {
    float n = 0.f, den = 0.f;
#pragma unroll
    for (int s = 0; s < KS; ++s) {
      const size_t o = base + (size_t)s * (NB * NB);
      n += pn[o];
      den += pd[o];
    }
    float cv = 0.f, ev = 0.f;
#pragma unroll
    for (int s = 0; s < 8; ++s) { cv += cpart[s * NB + i]; ev += epart[s * NB + i]; }
    out[base] = (n + cv) / (sqrtf(fmaxf(den + ev, 0.0f)) + 1e-8f);
  }
}

extern "C" void kernel_launch(void* const* d_in, const int* in_sizes, int n_in,
                              void* d_out, int out_size, void* d_ws, size_t ws_size,
                              hipStream_t stream) {
  const float* img = (const float*)d_in[0];
  const float* cap = (const float*)d_in[1];
  const int* lens = (const int*)d_in[2];
  const float* Wg1 = (const float*)d_in[3];
  const float* bg1 = (const float*)d_in[4];
  const float* Wg2 = (const float*)d_in[5];
  const float* bg2 = (const float*)d_in[6];
  const float* Wb1 = (const float*)d_in[7];
  const float* bb1 = (const float*)d_in[8];
  const float* Wb2 = (const float*)d_in[9];
  const float* bb2 = (const float*)d_in[10];
  float* out = (float*)d_out;

  float* w = (float*)d_ws;
  float* fullsum = w; w += 2 * NB * NDIM;  // 2 MB
  float* fullsq = w;  w += 2 * NB * NDIM;  // 2 MB
  float* msum = w;    w += 2 * NB * NDIM;  // 2 MB
  float* hpart = w;   w += 16 * NB * HDIM; // 2 MB
  float* pooled = w;  w += NB * NDIM;      // 1 MB
  float* uarr = w;    w += NB * NDIM;      // 1 MB
  float* aarr = w;    w += NB * NDIM;      // 1 MB
  float* bvarr = w;   w += NB * NDIM;      // 1 MB
  float* repr = w;    w += NB * NDIM;      // 1 MB (dedicated)
  float* imgn = w;    w += NB * NDIM;      // 1 MB (dedicated — k_l2 idempotent)
  float* cpart = w;   w += 8 * NB;
  float* epart = w;   w += 8 * NB;
  // pn/pd (KS=4: 262144 floats each) alias fullsum (dead after k_mid)
  float* pn = fullsum;
  float* pd = fullsum + 262144;

  hipLaunchKernelGGL(k_front, dim3(768), dim3(256), 0, stream, img, cap, lens, fullsum, fullsq,
                     msum, repr, imgn, R_FRONT);
  hipLaunchKernelGGL(k_mid, dim3(528), dim3(512), 0, stream, fullsum, fullsq, msum, lens, repr,
                     Wg1, Wb1, pooled, hpart, R_MID);
  hipLaunchKernelGGL(k_l2, dim3(32, 8), dim3(512), 0, stream, hpart, bg1, bb1, Wg2, bg2, Wb2,
                     bb2, imgn, uarr, aarr, bvarr, cpart, epart, R_L2);
  hipLaunchKernelGGL(k_simtile, dim3(8, 8, KS), dim3(256), 0, stream, uarr, aarr, bvarr, pooled,
                     pn, pd, R_ST);
  hipLaunchKernelGGL(k_reduce, dim3(NB), dim3(256), 0, stream, pn, pd, cpart, epart, out, R_RED);
}

// Round 10
// 70.031 us; speedup vs baseline: 12.2193x; 12.2193x over previous
//
#include <hip/hip_runtime.h>
#include <math.h>

#define NDIM 1024
#define HDIM 128
#define NB 256
#define NT 72
#define NR 36
#define KS 4  // split-K for simtile

__device__ __forceinline__ float wave_sum(float v) {
#pragma unroll
  for (int off = 32; off > 0; off >>= 1) v += __shfl_down(v, off, 64);
  return v;
}

__device__ __forceinline__ float dot4(const float4 a, const float4 b) {
  return a.x * b.x + a.y * b.y + a.z * b.z + a.w * b.w;
}

// K1: blocks 0..511 cap partial sums; 512..767 image mean + l2norm.
__global__ __launch_bounds__(256) void k_front(const float* __restrict__ img,
                                               const float* __restrict__ cap,
                                               const int* __restrict__ lens,
                                               float* __restrict__ fs, float* __restrict__ fq,
                                               float* __restrict__ ms, float* __restrict__ repr,
                                               float* __restrict__ imgn) {
  const int bid = blockIdx.x, tid = threadIdx.x;
  __shared__ float red[4];
  __shared__ float sInv;
  if (bid < 512) {
    const int b = bid & 255;
    const int half = bid >> 8;
    const int len = lens[b];
    const int t0 = half * 36;
    const float* base = cap + (size_t)b * NT * NDIM + (size_t)t0 * NDIM + tid * 4;
    float fsx = 0.f, fsy = 0.f, fsz = 0.f, fsw = 0.f;
    float fqx = 0.f, fqy = 0.f, fqz = 0.f, fqw = 0.f;
    float msx = 0.f, msy = 0.f, msz = 0.f, msw = 0.f;
#pragma unroll 12
    for (int tt = 0; tt < 36; ++tt) {
      const float4 v = *reinterpret_cast<const float4*>(base + tt * NDIM);
      fsx += v.x; fsy += v.y; fsz += v.z; fsw += v.w;
      fqx += v.x * v.x; fqy += v.y * v.y; fqz += v.z * v.z; fqw += v.w * v.w;
      if (t0 + tt < len) { msx += v.x; msy += v.y; msz += v.z; msw += v.w; }
    }
    const int o = (half * NB + b) * NDIM + tid * 4;
    *reinterpret_cast<float4*>(fs + o) = make_float4(fsx, fsy, fsz, fsw);
    *reinterpret_cast<float4*>(fq + o) = make_float4(fqx, fqy, fqz, fqw);
    *reinterpret_cast<float4*>(ms + o) = make_float4(msx, msy, msz, msw);
  } else {
    const int b = bid - 512;
    const float* base = img + (size_t)b * NR * NDIM + tid * 4;
    float sx = 0.f, sy = 0.f, sz = 0.f, sw = 0.f;
#pragma unroll 12
    for (int r = 0; r < NR; ++r) {
      const float4 v = *reinterpret_cast<const float4*>(base + r * NDIM);
      sx += v.x; sy += v.y; sz += v.z; sw += v.w;
    }
    const float inv = 1.0f / (float)NR;
    sx *= inv; sy *= inv; sz *= inv; sw *= inv;
    *reinterpret_cast<float4*>(repr + (size_t)b * NDIM + tid * 4) = make_float4(sx, sy, sz, sw);
    const float sq = wave_sum(sx * sx + sy * sy + sz * sz + sw * sw);
    const int lane = tid & 63, wv = tid >> 6;
    if (lane == 0) red[wv] = sq;
    __syncthreads();
    if (tid == 0) sInv = 1.0f / (sqrtf(red[0] + red[1] + red[2] + red[3]) + 1e-8f);
    __syncthreads();
    const float iv = sInv;
    *reinterpret_cast<float4*>(imgn + (size_t)b * NDIM + tid * 4) =
        make_float4(sx * iv, sy * iv, sz * iv, sw * iv);
  }
}

// K2: blocks 0..15 BN stats + pooled; blocks 16..527 layer1 split-K GEMM.
__global__ __launch_bounds__(512) void k_mid(const float* __restrict__ fs,
                                             const float* __restrict__ fq,
                                             const float* __restrict__ ms,
                                             const int* __restrict__ lens,
                                             const float* __restrict__ repr,
                                             const float* __restrict__ Wg1,
                                             const float* __restrict__ Wb1,
                                             float* __restrict__ pooled,
                                             float* __restrict__ hpart) {
  const int bid = blockIdx.x, tid = threadIdx.x;
  __shared__ float ss[8][64], sq2[8][64], smu[64], srs[64];
  __shared__ float shr[8][128];
  __shared__ float sacc[8][128][8];
  if (bid < 16) {
    const int d0 = bid * 64, dloc = tid & 63, grp = tid >> 6;
    float s = 0.f, q = 0.f;
    const int r0 = grp * 64;
#pragma unroll 8
    for (int r = r0; r < r0 + 64; ++r) {
      s += fs[(size_t)r * NDIM + d0 + dloc];
      q += fq[(size_t)r * NDIM + d0 + dloc];
    }
    ss[grp][dloc] = s;
    sq2[grp][dloc] = q;
    __syncthreads();
    if (tid < 64) {
      float S = 0.f, Q = 0.f;
#pragma unroll
      for (int g2 = 0; g2 < 8; ++g2) { S += ss[g2][tid]; Q += sq2[g2][tid]; }
      const float invN = 1.0f / (float)(NB * NT);
      const float mu = S * invN;
      const float var = Q * invN - mu * mu;
      smu[tid] = mu;
      srs[tid] = 1.0f / sqrtf(var + 1e-5f);
    }
    __syncthreads();
    const int dcol = tid & 63, brow = tid >> 6;
    const float mu = smu[dcol], rs = srs[dcol];
#pragma unroll 4
    for (int b = brow; b < NB; b += 8) {
      const float invl = 1.0f / (float)lens[b];
      const float m = ms[(size_t)b * NDIM + d0 + dcol] + ms[(size_t)(NB + b) * NDIM + d0 + dcol];
      pooled[(size_t)b * NDIM + d0 + dcol] = (m * invl - mu) * rs;
    }
  } else {
    const int idx = bid - 16;
    const int g = idx & 31, br = (idx >> 5) & 1, ks = idx >> 6;
    const int b0 = g * 8;
    const int kbase = ks * 128;
    const int h2 = tid & 63;
    const int ksub = tid >> 6;
    const float* __restrict__ W = br ? Wb1 : Wg1;
    {
      const int im = tid >> 6, c2 = (tid & 63) * 2;
      *reinterpret_cast<float2*>(&shr[im][c2]) =
          *reinterpret_cast<const float2*>(repr + (size_t)(b0 + im) * NDIM + kbase + c2);
    }
    __syncthreads();
    float acc0[8] = {0, 0, 0, 0, 0, 0, 0, 0}, acc1[8] = {0, 0, 0, 0, 0, 0, 0, 0};
#pragma unroll
    for (int q = 0; q < 4; ++q) {
      const int dl = ksub * 16 + q * 4;
      const float* wq = W + (size_t)(kbase + dl) * HDIM + h2;
      const float wa0 = wq[0], wa1 = wq[128], wa2 = wq[256], wa3 = wq[384];
      const float wb0 = wq[64], wb1 = wq[192], wb2 = wq[320], wb3 = wq[448];
#pragma unroll
      for (int i = 0; i < 8; ++i) {
        const float4 s = *reinterpret_cast<const float4*>(&shr[i][dl]);
        acc0[i] += s.x * wa0 + s.y * wa1 + s.z * wa2 + s.w * wa3;
        acc1[i] += s.x * wb0 + s.y * wb1 + s.z * wb2 + s.w * wb3;
      }
    }
#pragma unroll
    for (int i = 0; i < 8; ++i) {
      sacc[ksub][h2][i] = acc0[i];
      sacc[ksub][h2 + 64][i] = acc1[i];
    }
    __syncthreads();
#pragma unroll
    for (int v = tid; v < 1024; v += 512) {
      const int hh = v & 127, im = v >> 7;
      float s = 0.f;
#pragma unroll
      for (int k2 = 0; k2 < 8; ++k2) s += sacc[k2][hh][im];
      hpart[(((size_t)ks * 2 + br) * NB + b0 + im) * HDIM + hh] = s;
    }
  }
}

// K3 (redundancy-free): hidden-reduce + layer2 + derived u,a,2bv,c,e.
// grid (32 imggrp of 8, 8 dgrp of 128) x 512 thr.
// Phase B: thread = (dq: 4 d, kseg: 16 h, br); register-tiles ALL 8 images
// so each W2 element is loaded exactly once per block (128 KB vs 1 MB).
__global__ __launch_bounds__(512) void k_l2(
    const float* __restrict__ hpart, const float* __restrict__ bg1,
    const float* __restrict__ bb1, const float* __restrict__ Wg2,
    const float* __restrict__ bg2, const float* __restrict__ Wb2,
    const float* __restrict__ bb2, const float* __restrict__ imgn, float* __restrict__ uarr,
    float* __restrict__ aarr, float* __restrict__ bvarr, float* __restrict__ cpart,
    float* __restrict__ epart) {
  const int gb = blockIdx.x, dgrp = blockIdx.y;
  const int b0 = gb * 8;
  const int tid = threadIdx.x;
  __shared__ float shh[2][8][HDIM];        // 8 KB hidden after relu
  __shared__ float sacc[2][8][8][HDIM];    // 64 KB [br][kseg][im][dloc]

  // ---- phase A: reduce hpart over the 8 k-slabs, add bias, relu ----
  {
    const int hh4 = (tid & 31) * 4;
    const int imA = (tid >> 5) & 7;
    const int brA = tid >> 8;
    float4 acc = make_float4(0.f, 0.f, 0.f, 0.f);
    const float* hp = hpart + ((size_t)brA * NB + b0 + imA) * HDIM + hh4;
#pragma unroll
    for (int ks = 0; ks < 8; ++ks) {
      const float4 v = *reinterpret_cast<const float4*>(hp + (size_t)ks * 2 * NB * HDIM);
      acc.x += v.x; acc.y += v.y; acc.z += v.z; acc.w += v.w;
    }
    const float4 bias = *reinterpret_cast<const float4*>((brA ? bb1 : bg1) + hh4);
    *reinterpret_cast<float4*>(&shh[brA][imA][hh4]) =
        make_float4(fmaxf(acc.x + bias.x, 0.f), fmaxf(acc.y + bias.y, 0.f),
                    fmaxf(acc.z + bias.z, 0.f), fmaxf(acc.w + bias.w, 0.f));
  }
  __syncthreads();

  // ---- phase B: W2 slab loaded once; 8-image register tile ----
  {
    const int dq = tid & 31;          // 4-float column in the 128-d slab
    const int kseg = (tid >> 5) & 7;  // 16-h segment
    const int br = tid >> 8;          // branch
    const int d = dgrp * 128 + dq * 4;
    const float* __restrict__ W = br ? Wb2 : Wg2;
    float4 acc[8];
#pragma unroll
    for (int im = 0; im < 8; ++im) acc[im] = make_float4(0.f, 0.f, 0.f, 0.f);
    const int h0 = kseg * 16;
#pragma unroll
    for (int hh = 0; hh < 16; ++hh) {
      const int h = h0 + hh;
      const float4 w4 = *reinterpret_cast<const float4*>(W + (size_t)h * NDIM + d);
#pragma unroll
      for (int im = 0; im < 8; ++im) {
        const float hv = shh[br][im][h];
        acc[im].x += hv * w4.x; acc[im].y += hv * w4.y;
        acc[im].z += hv * w4.z; acc[im].w += hv * w4.w;
      }
    }
#pragma unroll
    for (int im = 0; im < 8; ++im)
      *reinterpret_cast<float4*>(&sacc[br][kseg][im][dq * 4]) = acc[im];
  }
  __syncthreads();

  // ---- phase C: combine 8 ksegs + epilogue; one wave per image ----
  {
    const int imC = tid >> 6;        // 0..7 (full wave each)
    const int dl = (tid & 63) * 2;   // 2 d per thread
    float g0 = 0.f, g1 = 0.f, t0 = 0.f, t1 = 0.f;
#pragma unroll
    for (int ks = 0; ks < 8; ++ks) {
      g0 += sacc[0][ks][imC][dl];
      g1 += sacc[0][ks][imC][dl + 1];
      t0 += sacc[1][ks][imC][dl];
      t1 += sacc[1][ks][imC][dl + 1];
    }
    const int d = dgrp * 128 + dl;
    const float2 bgv = *reinterpret_cast<const float2*>(bg2 + d);
    const float2 bbv = *reinterpret_cast<const float2*>(bb2 + d);
    const float ox0 = g0 + bgv.x + 1.0f, ox1 = g1 + bgv.y + 1.0f;
    const float tb0 = t0 + bbv.x, tb1 = t1 + bbv.y;
    const size_t o = (size_t)(b0 + imC) * NDIM + d;
    const float2 nv = *reinterpret_cast<const float2*>(imgn + o);
    *reinterpret_cast<float2*>(uarr + o) = make_float2(nv.x * ox0, nv.y * ox1);
    *reinterpret_cast<float2*>(aarr + o) = make_float2(ox0 * ox0, ox1 * ox1);
    *reinterpret_cast<float2*>(bvarr + o) = make_float2(2.0f * ox0 * tb0, 2.0f * ox1 * tb1);
    const float c = wave_sum(nv.x * tb0 + nv.y * tb1);
    const float e = wave_sum(tb0 * tb0 + tb1 * tb1);
    if ((tid & 63) == 0) {
      cpart[dgrp * NB + b0 + imC] = c;
      epart[dgrp * NB + b0 + imC] = e;
    }
  }
}

// K4: 3-dot tile kernel; 32x32 tile, 2x2 per thread, q=p^2 in regs,
// denominator pre-combined. grid (8,8,KS=4), 256 thr, K-chunk 256.
__global__ __launch_bounds__(256) void k_simtile(
    const float* __restrict__ uarr, const float* __restrict__ aarr,
    const float* __restrict__ bvarr, const float* __restrict__ pooled,
    float* __restrict__ pn, float* __restrict__ pd) {
  __shared__ float su[32][36], sa[32][36], sb[32][36], sp[32][36];
  const int tid = threadIdx.x;
  const int tx = tid & 15, ty = tid >> 4;
  const int i0 = blockIdx.x * 32, j0 = blockIdx.y * 32;
  const int k0 = blockIdx.z * (NDIM / KS);
  const int lr = tid >> 3;       // 0..31
  const int lc = (tid & 7) * 4;  // 0..28
  const int s = blockIdx.z;
  float an[2][2] = {{0.f, 0.f}, {0.f, 0.f}}, ad[2][2] = {{0.f, 0.f}, {0.f, 0.f}};
  for (int dc = k0; dc < k0 + NDIM / KS; dc += 32) {
    __syncthreads();
    *reinterpret_cast<float4*>(&su[lr][lc]) =
        *reinterpret_cast<const float4*>(uarr + (size_t)(i0 + lr) * NDIM + dc + lc);
    *reinterpret_cast<float4*>(&sa[lr][lc]) =
        *reinterpret_cast<const float4*>(aarr + (size_t)(i0 + lr) * NDIM + dc + lc);
    *reinterpret_cast<float4*>(&sb[lr][lc]) =
        *reinterpret_cast<const float4*>(bvarr + (size_t)(i0 + lr) * NDIM + dc + lc);
    *reinterpret_cast<float4*>(&sp[lr][lc]) =
        *reinterpret_cast<const float4*>(pooled + (size_t)(j0 + lr) * NDIM + dc + lc);
    __syncthreads();
#pragma unroll
    for (int dd = 0; dd < 32; dd += 4) {
      float4 rp[2], rq[2];
#pragma unroll
      for (int n = 0; n < 2; ++n) {
        rp[n] = *reinterpret_cast<const float4*>(&sp[ty + 16 * n][dd]);
        rq[n] = make_float4(rp[n].x * rp[n].x, rp[n].y * rp[n].y, rp[n].z * rp[n].z,
                            rp[n].w * rp[n].w);
      }
#pragma unroll
      for (int m = 0; m < 2; ++m) {
        const float4 ru = *reinterpret_cast<const float4*>(&su[tx + 16 * m][dd]);
        const float4 ra = *reinterpret_cast<const float4*>(&sa[tx + 16 * m][dd]);
        const float4 rb = *reinterpret_cast<const float4*>(&sb[tx + 16 * m][dd]);
#pragma unroll
        for (int n = 0; n < 2; ++n) {
          an[m][n] += dot4(ru, rp[n]);
          ad[m][n] += dot4(ra, rq[n]) + dot4(rb, rp[n]);
        }
      }
    }
  }
#pragma unroll
  for (int m = 0; m < 2; ++m) {
#pragma unroll
    for (int n = 0; n < 2; ++n) {
      const int i = i0 + tx + 16 * m, j = j0 + ty + 16 * n;
      const size_t o = ((size_t)s * NB + j) * NB + i;
      pn[o] = an[m][n];
      pd[o] = ad[m][n];
    }
  }
}

// K5: split-K combine + epilogue
__global__ __launch_bounds__(256) void k_reduce(const float* __restrict__ pn,
                                                const float* __restrict__ pd,
                                                const float* __restrict__ cpart,
                                                const float* __restrict__ epart,
                                                float* __restrict__ out) {
  const int j = blockIdx.x, i = threadIdx.x;
  const size_t base = (size_t)j * NB + i;
  float n = 0.f, den = 0.f;
#pragma unroll
  for (int s = 0; s < KS; ++s) {
    const size_t o = base + (size_t)s * (NB * NB);
    n += pn[o];
    den += pd[o];
  }
  float cv = 0.f, ev = 0.f;
#pragma unroll
  for (int s = 0; s < 8; ++s) { cv += cpart[s * NB + i]; ev += epart[s * NB + i]; }
  out[base] = (n + cv) / (sqrtf(fmaxf(den + ev, 0.0f)) + 1e-8f);
}

extern "C" void kernel_launch(void* const* d_in, const int* in_sizes, int n_in,
                              void* d_out, int out_size, void* d_ws, size_t ws_size,
                              hipStream_t stream) {
  const float* img = (const float*)d_in[0];
  const float* cap = (const float*)d_in[1];
  const int* lens = (const int*)d_in[2];
  const float* Wg1 = (const float*)d_in[3];
  const float* bg1 = (const float*)d_in[4];
  const float* Wg2 = (const float*)d_in[5];
  const float* bg2 = (const float*)d_in[6];
  const float* Wb1 = (const float*)d_in[7];
  const float* bb1 = (const float*)d_in[8];
  const float* Wb2 = (const float*)d_in[9];
  const float* bb2 = (const float*)d_in[10];
  float* out = (float*)d_out;

  float* w = (float*)d_ws;
  float* fullsum = w; w += 2 * NB * NDIM;  // 2 MB
  float* fullsq = w;  w += 2 * NB * NDIM;  // 2 MB
  float* msum = w;    w += 2 * NB * NDIM;  // 2 MB
  float* hpart = w;   w += 16 * NB * HDIM; // 2 MB
  float* pooled = w;  w += NB * NDIM;      // 1 MB
  float* uarr = w;    w += NB * NDIM;      // 1 MB
  float* aarr = w;    w += NB * NDIM;      // 1 MB
  float* bvarr = w;   w += NB * NDIM;      // 1 MB
  float* repr = w;    w += NB * NDIM;      // 1 MB (dedicated)
  float* imgn = w;    w += NB * NDIM;      // 1 MB (dedicated)
  float* cpart = w;   w += 8 * NB;
  float* epart = w;   w += 8 * NB;
  // pn/pd (KS=4: 262144 floats each) alias fullsum (dead after k_mid)
  float* pn = fullsum;
  float* pd = fullsum + 262144;

  hipLaunchKernelGGL(k_front, dim3(768), dim3(256), 0, stream, img, cap, lens, fullsum, fullsq,
                     msum, repr, imgn);
  hipLaunchKernelGGL(k_mid, dim3(528), dim3(512), 0, stream, fullsum, fullsq, msum, lens, repr,
                     Wg1, Wb1, pooled, hpart);
  hipLaunchKernelGGL(k_l2, dim3(32, 8), dim3(512), 0, stream, hpart, bg1, bb1, Wg2, bg2, Wb2,
                     bb2, imgn, uarr, aarr, bvarr, cpart, epart);
  hipLaunchKernelGGL(k_simtile, dim3(8, 8, KS), dim3(256), 0, stream, uarr, aarr, bvarr, pooled,
                     pn, pd);
  hipLaunchKernelGGL(k_reduce, dim3(NB), dim3(256), 0, stream, pn, pd, cpart, epart, out);
}